// Round 2
// baseline (2617.114 us; speedup 1.0000x reference)
//
#include <hip/hip_runtime.h>
#include <cstdint>
#include <cstddef>

// BiLSTM-CRF forward, MI355X fp32 implementation.
// Pipeline: prep -> proj1(emb gather GEMM) -> lstm1(512 chains) -> proj2(GEMM)
//           -> lstm2(64 chains) -> emission -> viterbi(+backtrace).
// Only valid (packed) tokens are computed; tail positions provably don't
// affect outputs (mask freezes LSTM2 state and Viterbi score/backtrace).
//
// R1: LSTM chain reworked to 256 threads x 2 gate-rows/thread:
//  - halves LDS h-broadcast traffic (was the per-step bottleneck)
//  - __launch_bounds__(256,1) so 256 VGPRs of Whh stay register-resident
//    (R0 showed VGPR_Count=116 => weights were re-fetched every step)
//  - depth-1 prefetch of next step's xproj row

#define B_    32
#define NSEG_ 8
#define S_    128
#define T_    1024
#define E_    256
#define HD_   128
#define G_    512   // 4*HD
#define K_    16

// ---------------- prep: seg offsets, fused bias, transposed Wih ----------------
__global__ void prep_kernel(const int* __restrict__ lengths,
                            int* __restrict__ seg_off, int* __restrict__ new_len,
                            const float* __restrict__ bih_f, const float* __restrict__ bhh_f,
                            const float* __restrict__ bih_b, const float* __restrict__ bhh_b,
                            float* __restrict__ bias1,
                            const float* __restrict__ Wih_f, const float* __restrict__ Wih_b,
                            float* __restrict__ WT1)
{
    int gtid = blockIdx.x * blockDim.x + threadIdx.x;
    if (gtid < B_) {
        int acc = 0;
        for (int s = 0; s < NSEG_; s++) { seg_off[gtid*NSEG_ + s] = acc; acc += lengths[gtid*NSEG_ + s]; }
        new_len[gtid] = acc;
    }
    if (gtid < 512)       bias1[gtid] = bih_f[gtid] + bhh_f[gtid];
    else if (gtid < 1024) bias1[gtid] = bih_b[gtid-512] + bhh_b[gtid-512];
    // WT1[k][j] (256 x 1024): j<512 -> Wih_f[j][k], else Wih_b[j-512][k]
    for (int e = gtid; e < 256*1024; e += gridDim.x * blockDim.x) {
        int k = e >> 10, j = e & 1023;
        WT1[e] = (j < 512) ? Wih_f[j*E_ + k] : Wih_b[(j-512)*E_ + k];
    }
}

// ---------------- projection GEMM: xproj[b][p][j] = A[p][:] . WT1[:][j] + bias1[j] ----------------
// MODE 0: A row = emb_table[texts[...]] (gather); MODE 1: A row = lstm_packed[b][p][:]
template <int MODE>
__global__ void __launch_bounds__(256, 4)
proj_kernel(const int* __restrict__ texts, const float* __restrict__ emb,
            const float* __restrict__ WT1, const float* __restrict__ bias1,
            const float* __restrict__ lstm_packed, float* __restrict__ xproj,
            const int* __restrict__ seg_off, const int* __restrict__ new_len)
{
    int b  = blockIdx.z;
    int nl = new_len[b];
    int p0 = blockIdx.x * 32;
    if (p0 >= nl) return;
    int j0 = blockIdx.y * 256;

    __shared__ __align__(16) float As[32][256];
    __shared__ const float* rowp[32];
    int tid = threadIdx.x;
    if (tid < 32) {
        int p = p0 + tid;
        const float* r = emb;  // dummy row for invalid p
        if (p < nl) {
            if (MODE == 0) {
                int sg = 0;
                #pragma unroll
                for (int q = 1; q < NSEG_; q++) if (seg_off[b*NSEG_ + q] <= p) sg = q;
                int t   = p - seg_off[b*NSEG_ + sg];
                int tok = texts[(b*NSEG_ + sg)*S_ + t];
                r = emb + (size_t)tok * E_;
            } else {
                r = lstm_packed + ((size_t)b*T_ + p) * 256;
            }
        }
        rowp[tid] = r;
    }
    __syncthreads();
    #pragma unroll 4
    for (int i = 0; i < 32; i++) As[i][tid] = rowp[i][tid];
    __syncthreads();

    int pg = tid >> 6;        // 0..3 -> rows pg*8 .. pg*8+7
    int jg = tid & 63;        // cols j0 + jg*4 .. +3
    int j  = j0 + jg*4;
    float acc[8][4];
    #pragma unroll
    for (int i = 0; i < 8; i++) { acc[i][0]=0.f; acc[i][1]=0.f; acc[i][2]=0.f; acc[i][3]=0.f; }

    const float* wbase = WT1 + j;
    for (int k = 0; k < 256; k += 4) {
        float4 w0 = *(const float4*)(wbase + (size_t)(k+0)*1024);
        float4 w1 = *(const float4*)(wbase + (size_t)(k+1)*1024);
        float4 w2 = *(const float4*)(wbase + (size_t)(k+2)*1024);
        float4 w3 = *(const float4*)(wbase + (size_t)(k+3)*1024);
        #pragma unroll
        for (int i = 0; i < 8; i++) {
            float4 a = *(const float4*)&As[pg*8 + i][k];
            acc[i][0] = fmaf(a.w, w3.x, fmaf(a.z, w2.x, fmaf(a.y, w1.x, fmaf(a.x, w0.x, acc[i][0]))));
            acc[i][1] = fmaf(a.w, w3.y, fmaf(a.z, w2.y, fmaf(a.y, w1.y, fmaf(a.x, w0.y, acc[i][1]))));
            acc[i][2] = fmaf(a.w, w3.z, fmaf(a.z, w2.z, fmaf(a.y, w1.z, fmaf(a.x, w0.z, acc[i][2]))));
            acc[i][3] = fmaf(a.w, w3.w, fmaf(a.z, w2.w, fmaf(a.y, w1.w, fmaf(a.x, w0.w, acc[i][3]))));
        }
    }
    float4 bs = *(const float4*)(bias1 + j);
    #pragma unroll
    for (int i = 0; i < 8; i++) {
        int p = p0 + pg*8 + i;
        if (p < nl) {
            float4 r;
            r.x = acc[i][0] + bs.x; r.y = acc[i][1] + bs.y;
            r.z = acc[i][2] + bs.z; r.w = acc[i][3] + bs.w;
            *(float4*)(xproj + (((size_t)b*T_ + p) << 10) + j) = r;
        }
    }
}

// ---------------- LSTM chain: 256 threads, thread t owns gate rows t and t+256 ----------------
// t in [0,128):   rows t (gate i), t+256 (gate g);  also applies nonlinearity, owns c[t]
// t in [128,256): rows t (gate f), t+256 (gate o);  pre-applies sigmoid, ships via fo_sh
__device__ __forceinline__ float sig_f(float x) { return 1.0f / (1.0f + __expf(-x)); }
__device__ __forceinline__ float tanh_f(float x) {
    float xc = fminf(fmaxf(x, -15.0f), 15.0f);
    float e  = __expf(-2.0f * xc);
    return (1.0f - e) / (1.0f + e);
}

__device__ __forceinline__ void lstm_chain(
    const float* __restrict__ Whh,     // [512][128] row-major, this dir
    const float* __restrict__ xp,      // xproj for this b: [1024][1024] (bias folded in)
    float* __restrict__ outp,          // lstm_packed for this b: [1024][256]
    int p_base, int len, int dir, int rev,
    const float* __restrict__ h0, const float* __restrict__ c0,
    float* __restrict__ hT, float* __restrict__ cT)
{
    __shared__ __align__(16) float  h_sh[HD_];
    __shared__ __align__(8)  float2 fo_sh[HD_];
    int t = threadIdx.x;   // 0..255

    // Whh rows t and t+256, register-resident (256 VGPRs; launch_bounds(256,1))
    float4 wa[32], wb[32];
    {
        const float4* wr0 = (const float4*)(Whh + (size_t)t * HD_);
        const float4* wr1 = (const float4*)(Whh + (size_t)(t + 256) * HD_);
        #pragma unroll
        for (int i = 0; i < 32; i++) { wa[i] = wr0[i]; wb[i] = wr1[i]; }
    }

    float c_reg = 0.0f;
    if (t < HD_) {
        h_sh[t] = h0 ? h0[t] : 0.0f;
        c_reg   = c0 ? c0[t] : 0.0f;
    }

    const int col0 = dir * G_ + t;     // x column of row t
    const int col1 = col0 + 256;       // x column of row t+256
    {
        int p0 = p_base + (rev ? (len - 1) : 0);
        // fallthrough into loop with xv preloaded
    }
    int pfirst = p_base + (rev ? (len - 1) : 0);
    float xv0 = xp[((size_t)pfirst << 10) + col0];
    float xv1 = xp[((size_t)pfirst << 10) + col1];
    __syncthreads();

    for (int s = 0; s < len; s++) {
        // prefetch next step's x (address independent of state)
        int sn = (s + 1 < len) ? (s + 1) : s;
        int pn = p_base + (rev ? (len - 1 - sn) : sn);
        float nx0 = xp[((size_t)pn << 10) + col0];
        float nx1 = xp[((size_t)pn << 10) + col1];

        float a0x=0.f,a0y=0.f,a0z=0.f,a0w=0.f;
        float a1x=0.f,a1y=0.f,a1z=0.f,a1w=0.f;
        const float4* hv = (const float4*)h_sh;
        #pragma unroll
        for (int i = 0; i < 32; i++) {
            float4 h4 = hv[i];
            a0x = fmaf(h4.x, wa[i].x, a0x);
            a0y = fmaf(h4.y, wa[i].y, a0y);
            a0z = fmaf(h4.z, wa[i].z, a0z);
            a0w = fmaf(h4.w, wa[i].w, a0w);
            a1x = fmaf(h4.x, wb[i].x, a1x);
            a1y = fmaf(h4.y, wb[i].y, a1y);
            a1z = fmaf(h4.z, wb[i].z, a1z);
            a1w = fmaf(h4.w, wb[i].w, a1w);
        }
        float g0 = xv0 + ((a0x + a0y) + (a0z + a0w));   // t<128: i_t   else f_{t-128}
        float g1 = xv1 + ((a1x + a1y) + (a1z + a1w));   // t<128: gg_t  else o_{t-128}

        if (t >= HD_) fo_sh[t - HD_] = make_float2(sig_f(g0), sig_f(g1));
        __syncthreads();   // fo written; all h_sh reads of this step done

        int p = p_base + (rev ? (len - 1 - s) : s);
        if (t < HD_) {
            float2 fo = fo_sh[t];
            float cn = fo.x * c_reg + sig_f(g0) * tanh_f(g1);
            c_reg = cn;
            float hn = fo.y * tanh_f(cn);
            h_sh[t] = hn;
            outp[(size_t)p * 256 + dir * HD_ + t] = hn;
        }
        __syncthreads();   // h_sh updated before next matvec
        xv0 = nx0; xv1 = nx1;
    }
    if (hT != nullptr && t < HD_) { hT[t] = h_sh[t]; cT[t] = c_reg; }
}

__global__ void __launch_bounds__(256, 1)
lstm1_kernel(const int* __restrict__ lengths, const int* __restrict__ seg_off,
             const float* __restrict__ Whh_f, const float* __restrict__ Whh_b,
             const float* __restrict__ xproj, float* __restrict__ lstm_packed,
             float* __restrict__ hinit, float* __restrict__ cinit)
{
    int cid = blockIdx.x;                 // 512 = 32b * 8seg * 2dir
    int b = cid >> 4, seg = (cid >> 1) & 7, dir = cid & 1;
    int len = lengths[b*NSEG_ + seg];
    int pb  = seg_off[b*NSEG_ + seg];
    const float* Whh = dir ? Whh_b : Whh_f;
    float* hT = nullptr; float* cT = nullptr;
    if (seg == NSEG_ - 1) {               // final states feed LSTM2 init
        hT = hinit + (dir*B_ + b)*HD_;
        cT = cinit + (dir*B_ + b)*HD_;
    }
    lstm_chain(Whh, xproj + ((size_t)b << 20), lstm_packed + (size_t)b*T_*256,
               pb, len, dir, dir, nullptr, nullptr, hT, cT);
}

__global__ void __launch_bounds__(256, 1)
lstm2_kernel(const int* __restrict__ new_len,
             const float* __restrict__ Whh_f, const float* __restrict__ Whh_b,
             const float* __restrict__ xproj, float* __restrict__ lstm_packed,
             const float* __restrict__ hinit, const float* __restrict__ cinit)
{
    int cid = blockIdx.x;                 // 64 = 32b * 2dir
    int b = cid >> 1, dir = cid & 1;
    int len = new_len[b];
    const float* Whh = dir ? Whh_b : Whh_f;
    lstm_chain(Whh, xproj + ((size_t)b << 20), lstm_packed + (size_t)b*T_*256,
               0, len, dir, dir,
               hinit + (dir*B_ + b)*HD_, cinit + (dir*B_ + b)*HD_,
               nullptr, nullptr);
}

// ---------------- emission: em[b][p][s] = lstm2[b][p][:] . Wlin[s][:] + blin[s] ----------------
__global__ void __launch_bounds__(256)
emission_kernel(const float* __restrict__ lstm_packed, const float* __restrict__ Wlin,
                const float* __restrict__ blin, float* __restrict__ emis,
                const int* __restrict__ new_len)
{
    int b  = blockIdx.y;
    int nl = new_len[b];
    int p0 = blockIdx.x * 16;
    if (p0 >= nl) return;
    int pl = threadIdx.x >> 4, s = threadIdx.x & 15;
    int p  = p0 + pl;
    const float4* xr = (const float4*)(lstm_packed + ((size_t)b*T_ + p) * 256);
    const float4* wr = (const float4*)(Wlin + (size_t)s * 256);
    float ax = 0.f, ay = 0.f, az = 0.f, aw = 0.f;
    #pragma unroll
    for (int i = 0; i < 64; i++) {
        float4 a = xr[i]; float4 ww = wr[i];
        ax = fmaf(a.x, ww.x, ax); ay = fmaf(a.y, ww.y, ay);
        az = fmaf(a.z, ww.z, az); aw = fmaf(a.w, ww.w, aw);
    }
    if (p < nl) emis[((size_t)b*T_ + p)*K_ + s] = (ax + ay) + (az + aw) + blin[s];
}

// ---------------- Viterbi: one block (1 wave) per batch element ----------------
__global__ void __launch_bounds__(64)
viterbi_kernel(const float* __restrict__ emis, const float* __restrict__ start,
               const float* __restrict__ trans, const float* __restrict__ endv,
               const int* __restrict__ new_len, float* __restrict__ out)
{
    int b    = blockIdx.x;
    int nl   = new_len[b];
    int lane = threadIdx.x;          // 64 lanes: 4 q-groups x 16 states
    int s    = lane & 15, q4 = lane >> 4;

    __shared__ unsigned char hist[T_ * K_];   // 16 KB
    __shared__ unsigned char tagb[T_];

    float tr[4];
    #pragma unroll
    for (int jj = 0; jj < 4; jj++) tr[jj] = trans[(q4*4 + jj)*K_ + s];

    const float* em = emis + (size_t)b * T_ * K_;
    float sc = start[s] + em[s];     // p = 0 (always valid)

    for (int p = 1; p < nl; p++) {
        float e = em[p*K_ + s];
        float m = -3.4e38f; int a = 0;
        #pragma unroll
        for (int jj = 0; jj < 4; jj++) {
            int q   = q4*4 + jj;
            float sq = __shfl(sc, q, 16);
            float v  = sq + tr[jj];
            if (v > m) { m = v; a = q; }
        }
        #pragma unroll
        for (int d = 16; d < 64; d <<= 1) {
            float mo = __shfl_xor(m, d);
            int   ao = __shfl_xor(a, d);
            if (mo > m || (mo == m && ao < a)) { m = mo; a = ao; }
        }
        sc = m + e;
        if (lane < K_) hist[p*K_ + s] = (unsigned char)a;
    }

    // final = sc + end; best/argmax (first index on ties)
    float m = sc + endv[s]; int a = s;
    #pragma unroll
    for (int d = 1; d < 16; d <<= 1) {
        float mo = __shfl_xor(m, d);
        int   ao = __shfl_xor(a, d);
        if (mo > m || (mo == m && ao < a)) { m = mo; a = ao; }
    }
    int last = a;
    if (lane == 0) out[T_*B_ + b] = m;
    __syncthreads();

    for (int i = lane; i < T_; i += 64) tagb[i] = (unsigned char)last;
    __syncthreads();
    if (lane == 0) {
        int cur = last;
        for (int j = nl - 2; j >= 0; j--) {
            cur = hist[(j+1)*K_ + cur];
            tagb[j] = (unsigned char)cur;
        }
    }
    __syncthreads();
    for (int i = lane; i < T_; i += 64) out[(size_t)i*B_ + b] = (float)tagb[i];
}

// ---------------- host ----------------
extern "C" void kernel_launch(void* const* d_in, const int* in_sizes, int n_in,
                              void* d_out, int out_size, void* d_ws, size_t ws_size,
                              hipStream_t stream)
{
    (void)in_sizes; (void)n_in; (void)out_size; (void)ws_size;
    const int*   texts   = (const int*)  d_in[0];
    const int*   lengths = (const int*)  d_in[1];
    const float* emb     = (const float*)d_in[2];
    const float* Wih_f   = (const float*)d_in[3];
    const float* Whh_f   = (const float*)d_in[4];
    const float* bih_f   = (const float*)d_in[5];
    const float* bhh_f   = (const float*)d_in[6];
    const float* Wih_b   = (const float*)d_in[7];
    const float* Whh_b   = (const float*)d_in[8];
    const float* bih_b   = (const float*)d_in[9];
    const float* bhh_b   = (const float*)d_in[10];
    const float* Wlin    = (const float*)d_in[11];
    const float* blin    = (const float*)d_in[12];
    const float* c_start = (const float*)d_in[13];
    const float* c_trans = (const float*)d_in[14];
    const float* c_end   = (const float*)d_in[15];
    float* out = (float*)d_out;

    // workspace carve (~163 MB total, all 16B-aligned)
    char* w = (char*)d_ws;
    int*   seg_off     = (int*)(w);                      // 256 ints
    int*   new_len     = (int*)(w + 1024);               // 32 ints
    float* bias1       = (float*)(w + 4096);             // 1024 f
    float* WT1         = (float*)(w + 8192);             // 262144 f (1 MB)
    float* hinit       = (float*)(w + 8192 + 1048576);   // 8192 f
    float* cinit       = hinit + 8192;                   // 8192 f
    float* lstm_packed = cinit + 8192;                   // 32*1024*256 f (32 MB)
    float* xproj       = lstm_packed + (size_t)B_*T_*256;    // 32*1024*1024 f (128 MB)
    float* emis        = xproj + ((size_t)B_ << 20);         // 32*1024*16 f (2 MB)

    prep_kernel<<<128, 256, 0, stream>>>(lengths, seg_off, new_len,
                                         bih_f, bhh_f, bih_b, bhh_b, bias1,
                                         Wih_f, Wih_b, WT1);
    proj_kernel<0><<<dim3(32, 4, B_), 256, 0, stream>>>(texts, emb, WT1, bias1,
                                                        lstm_packed, xproj, seg_off, new_len);
    lstm1_kernel<<<512, 256, 0, stream>>>(lengths, seg_off, Whh_f, Whh_b,
                                          xproj, lstm_packed, hinit, cinit);
    proj_kernel<1><<<dim3(32, 4, B_), 256, 0, stream>>>(texts, emb, WT1, bias1,
                                                        lstm_packed, xproj, seg_off, new_len);
    lstm2_kernel<<<64, 256, 0, stream>>>(new_len, Whh_f, Whh_b,
                                         xproj, lstm_packed, hinit, cinit);
    emission_kernel<<<dim3(64, B_), 256, 0, stream>>>(lstm_packed, Wlin, blin, emis, new_len);
    viterbi_kernel<<<B_, 64, 0, stream>>>(emis, c_start, c_trans, c_end, new_len, out);
}

// Round 3
// 1856.705 us; speedup vs baseline: 1.4095x; 1.4095x over previous
//
#include <hip/hip_runtime.h>
#include <cstdint>
#include <cstddef>

// BiLSTM-CRF forward, MI355X fp32 implementation.
// Pipeline: prep -> proj1(emb gather GEMM) -> lstm1(512 chains) -> proj2(GEMM)
//           -> lstm2(64 chains) -> emission -> viterbi(+backtrace).
// Only valid (packed) tokens are computed; tail positions provably don't
// affect outputs (mask freezes LSTM2 state and Viterbi score/backtrace).
//
// R2: LSTM chain v3 — attack the two measured per-step costs:
//  (a) weight refetch from L2 (256KB/step): weights pinned in VGPRs via
//      opaque inline-asm ("+v") so the compiler cannot rematerialize loads.
//      Thread=(j,q): 4 gate rows x 32-k slice = 32 float4 = 128 VGPRs/thread;
//      whole Whh lives in the CU's register file (8 waves x 128).
//  (b) h-broadcast LDS traffic: K-split cuts ds_read_b128 count 4x
//      (64 instr/step vs 256 in R0). Partials via conflict-free psum[q][j].

#define B_    32
#define NSEG_ 8
#define S_    128
#define T_    1024
#define E_    256
#define HD_   128
#define G_    512   // 4*HD
#define K_    16

#define PIN4(v) asm volatile("" : "+v"((v).x), "+v"((v).y), "+v"((v).z), "+v"((v).w))

// ---------------- prep: seg offsets, fused bias, transposed Wih ----------------
__global__ void prep_kernel(const int* __restrict__ lengths,
                            int* __restrict__ seg_off, int* __restrict__ new_len,
                            const float* __restrict__ bih_f, const float* __restrict__ bhh_f,
                            const float* __restrict__ bih_b, const float* __restrict__ bhh_b,
                            float* __restrict__ bias1,
                            const float* __restrict__ Wih_f, const float* __restrict__ Wih_b,
                            float* __restrict__ WT1)
{
    int gtid = blockIdx.x * blockDim.x + threadIdx.x;
    if (gtid < B_) {
        int acc = 0;
        for (int s = 0; s < NSEG_; s++) { seg_off[gtid*NSEG_ + s] = acc; acc += lengths[gtid*NSEG_ + s]; }
        new_len[gtid] = acc;
    }
    if (gtid < 512)       bias1[gtid] = bih_f[gtid] + bhh_f[gtid];
    else if (gtid < 1024) bias1[gtid] = bih_b[gtid-512] + bhh_b[gtid-512];
    // WT1[k][j] (256 x 1024): j<512 -> Wih_f[j][k], else Wih_b[j-512][k]
    for (int e = gtid; e < 256*1024; e += gridDim.x * blockDim.x) {
        int k = e >> 10, j = e & 1023;
        WT1[e] = (j < 512) ? Wih_f[j*E_ + k] : Wih_b[(j-512)*E_ + k];
    }
}

// ---------------- projection GEMM: xproj[b][p][j] = A[p][:] . WT1[:][j] + bias1[j] ----------------
// MODE 0: A row = emb_table[texts[...]] (gather); MODE 1: A row = lstm_packed[b][p][:]
template <int MODE>
__global__ void __launch_bounds__(256, 4)
proj_kernel(const int* __restrict__ texts, const float* __restrict__ emb,
            const float* __restrict__ WT1, const float* __restrict__ bias1,
            const float* __restrict__ lstm_packed, float* __restrict__ xproj,
            const int* __restrict__ seg_off, const int* __restrict__ new_len)
{
    int b  = blockIdx.z;
    int nl = new_len[b];
    int p0 = blockIdx.x * 32;
    if (p0 >= nl) return;
    int j0 = blockIdx.y * 256;

    __shared__ __align__(16) float As[32][256];
    __shared__ const float* rowp[32];
    int tid = threadIdx.x;
    if (tid < 32) {
        int p = p0 + tid;
        const float* r = emb;  // dummy row for invalid p
        if (p < nl) {
            if (MODE == 0) {
                int sg = 0;
                #pragma unroll
                for (int q = 1; q < NSEG_; q++) if (seg_off[b*NSEG_ + q] <= p) sg = q;
                int t   = p - seg_off[b*NSEG_ + sg];
                int tok = texts[(b*NSEG_ + sg)*S_ + t];
                r = emb + (size_t)tok * E_;
            } else {
                r = lstm_packed + ((size_t)b*T_ + p) * 256;
            }
        }
        rowp[tid] = r;
    }
    __syncthreads();
    #pragma unroll 4
    for (int i = 0; i < 32; i++) As[i][tid] = rowp[i][tid];
    __syncthreads();

    int pg = tid >> 6;        // 0..3 -> rows pg*8 .. pg*8+7
    int jg = tid & 63;        // cols j0 + jg*4 .. +3
    int j  = j0 + jg*4;
    float acc[8][4];
    #pragma unroll
    for (int i = 0; i < 8; i++) { acc[i][0]=0.f; acc[i][1]=0.f; acc[i][2]=0.f; acc[i][3]=0.f; }

    const float* wbase = WT1 + j;
    for (int k = 0; k < 256; k += 4) {
        float4 w0 = *(const float4*)(wbase + (size_t)(k+0)*1024);
        float4 w1 = *(const float4*)(wbase + (size_t)(k+1)*1024);
        float4 w2 = *(const float4*)(wbase + (size_t)(k+2)*1024);
        float4 w3 = *(const float4*)(wbase + (size_t)(k+3)*1024);
        #pragma unroll
        for (int i = 0; i < 8; i++) {
            float4 a = *(const float4*)&As[pg*8 + i][k];
            acc[i][0] = fmaf(a.w, w3.x, fmaf(a.z, w2.x, fmaf(a.y, w1.x, fmaf(a.x, w0.x, acc[i][0]))));
            acc[i][1] = fmaf(a.w, w3.y, fmaf(a.z, w2.y, fmaf(a.y, w1.y, fmaf(a.x, w0.y, acc[i][1]))));
            acc[i][2] = fmaf(a.w, w3.z, fmaf(a.z, w2.z, fmaf(a.y, w1.z, fmaf(a.x, w0.z, acc[i][2]))));
            acc[i][3] = fmaf(a.w, w3.w, fmaf(a.z, w2.w, fmaf(a.y, w1.w, fmaf(a.x, w0.w, acc[i][3]))));
        }
    }
    float4 bs = *(const float4*)(bias1 + j);
    #pragma unroll
    for (int i = 0; i < 8; i++) {
        int p = p0 + pg*8 + i;
        if (p < nl) {
            float4 r;
            r.x = acc[i][0] + bs.x; r.y = acc[i][1] + bs.y;
            r.z = acc[i][2] + bs.z; r.w = acc[i][3] + bs.w;
            *(float4*)(xproj + (((size_t)b*T_ + p) << 10) + j) = r;
        }
    }
}

// ---------------- LSTM chain v3 ----------------
__device__ __forceinline__ float sig_f(float x) { return 1.0f / (1.0f + __expf(-x)); }
__device__ __forceinline__ float tanh_f(float x) {
    float xc = fminf(fmaxf(x, -15.0f), 15.0f);
    float e  = __expf(-2.0f * xc);
    return (1.0f - e) / (1.0f + e);
}

__device__ __forceinline__ void lstm_chain(
    const float* __restrict__ Whh,     // [512][128] row-major, this dir
    const float* __restrict__ xp,      // xproj for this b: [1024][1024] (bias folded in)
    float* __restrict__ outp,          // lstm_packed for this b: [1024][256]
    int p_base, int len, int dir, int rev,
    const float* __restrict__ h0, const float* __restrict__ c0,
    float* __restrict__ hT, float* __restrict__ cT)
{
    __shared__ __align__(16) float  h_sh[HD_];
    __shared__ __align__(16) float4 psum[4*HD_];   // [q][j], conflict-free lane order
    int t = threadIdx.x;          // 0..511
    int j = t & 127, q = t >> 7;  // per-wave q is uniform -> h reads are pure broadcast

    // Weights: gate rows j+128g, k in [32q, 32q+32). Pinned into VGPRs.
    float4 w[4][8];
    #pragma unroll
    for (int g = 0; g < 4; g++) {
        const float4* wr = (const float4*)(Whh + (size_t)(j + 128*g) * HD_ + 32*q);
        #pragma unroll
        for (int i = 0; i < 8; i++) { w[g][i] = wr[i]; PIN4(w[g][i]); }
    }

    float c_reg = 0.0f;
    if (t < HD_) {
        h_sh[t] = h0 ? h0[t] : 0.0f;
        c_reg   = c0 ? c0[t] : 0.0f;
    }

    const float* xcol = xp + dir * G_ + j;   // gate g at +128*g
    float xi = 0.f, xf = 0.f, xg = 0.f, xo = 0.f;
    if (t < HD_ && len > 0) {
        int p0 = p_base + (rev ? (len - 1) : 0);
        const float* r = xcol + ((size_t)p0 << 10);
        xi = r[0]; xf = r[128]; xg = r[256]; xo = r[384];
    }
    __syncthreads();

    for (int s = 0; s < len; s++) {
        // partial dot over this thread's k-slice, all 4 gates of row j
        const float4* hv = (const float4*)h_sh + q * 8;
        float4 a0 = make_float4(0.f,0.f,0.f,0.f);
        float4 a1 = a0, a2 = a0, a3 = a0;
        #pragma unroll
        for (int i = 0; i < 8; i++) {
            float4 h4 = hv[i];
            a0.x = fmaf(h4.x, w[0][i].x, a0.x); a0.y = fmaf(h4.y, w[0][i].y, a0.y);
            a0.z = fmaf(h4.z, w[0][i].z, a0.z); a0.w = fmaf(h4.w, w[0][i].w, a0.w);
            a1.x = fmaf(h4.x, w[1][i].x, a1.x); a1.y = fmaf(h4.y, w[1][i].y, a1.y);
            a1.z = fmaf(h4.z, w[1][i].z, a1.z); a1.w = fmaf(h4.w, w[1][i].w, a1.w);
            a2.x = fmaf(h4.x, w[2][i].x, a2.x); a2.y = fmaf(h4.y, w[2][i].y, a2.y);
            a2.z = fmaf(h4.z, w[2][i].z, a2.z); a2.w = fmaf(h4.w, w[2][i].w, a2.w);
            a3.x = fmaf(h4.x, w[3][i].x, a3.x); a3.y = fmaf(h4.y, w[3][i].y, a3.y);
            a3.z = fmaf(h4.z, w[3][i].z, a3.z); a3.w = fmaf(h4.w, w[3][i].w, a3.w);
        }
        psum[q*128 + j] = make_float4((a0.x+a0.y)+(a0.z+a0.w),
                                      (a1.x+a1.y)+(a1.z+a1.w),
                                      (a2.x+a2.y)+(a2.z+a2.w),
                                      (a3.x+a3.y)+(a3.z+a3.w));
        __syncthreads();

        int p = p_base + (rev ? (len - 1 - s) : s);
        if (t < HD_) {
            // prefetch next step's x gates (address independent of state)
            float nxi = 0.f, nxf = 0.f, nxg = 0.f, nxo = 0.f;
            if (s + 1 < len) {
                int pn = p_base + (rev ? (len - 2 - s) : (s + 1));
                const float* r = xcol + ((size_t)pn << 10);
                nxi = r[0]; nxf = r[128]; nxg = r[256]; nxo = r[384];
            }
            float4 p0 = psum[j], p1 = psum[128 + j], p2 = psum[256 + j], p3 = psum[384 + j];
            float gi = xi + ((p0.x + p1.x) + (p2.x + p3.x));
            float gf = xf + ((p0.y + p1.y) + (p2.y + p3.y));
            float gg = xg + ((p0.z + p1.z) + (p2.z + p3.z));
            float go = xo + ((p0.w + p1.w) + (p2.w + p3.w));
            float cn = sig_f(gf) * c_reg + sig_f(gi) * tanh_f(gg);
            c_reg = cn;
            float hn = sig_f(go) * tanh_f(cn);
            h_sh[j] = hn;
            outp[(size_t)p * 256 + dir * HD_ + j] = hn;
            xi = nxi; xf = nxf; xg = nxg; xo = nxo;
        }
        __syncthreads();
    }
    if (hT != nullptr && t < HD_) { hT[t] = h_sh[t]; cT[t] = c_reg; }
}

__global__ void __launch_bounds__(512, 2)
lstm1_kernel(const int* __restrict__ lengths, const int* __restrict__ seg_off,
             const float* __restrict__ Whh_f, const float* __restrict__ Whh_b,
             const float* __restrict__ xproj, float* __restrict__ lstm_packed,
             float* __restrict__ hinit, float* __restrict__ cinit)
{
    int cid = blockIdx.x;                 // 512 = 32b * 8seg * 2dir
    int b = cid >> 4, seg = (cid >> 1) & 7, dir = cid & 1;
    int len = lengths[b*NSEG_ + seg];
    int pb  = seg_off[b*NSEG_ + seg];
    const float* Whh = dir ? Whh_b : Whh_f;
    float* hT = nullptr; float* cT = nullptr;
    if (seg == NSEG_ - 1) {               // final states feed LSTM2 init
        hT = hinit + (dir*B_ + b)*HD_;
        cT = cinit + (dir*B_ + b)*HD_;
    }
    lstm_chain(Whh, xproj + ((size_t)b << 20), lstm_packed + (size_t)b*T_*256,
               pb, len, dir, dir, nullptr, nullptr, hT, cT);
}

__global__ void __launch_bounds__(512, 2)
lstm2_kernel(const int* __restrict__ new_len,
             const float* __restrict__ Whh_f, const float* __restrict__ Whh_b,
             const float* __restrict__ xproj, float* __restrict__ lstm_packed,
             const float* __restrict__ hinit, const float* __restrict__ cinit)
{
    int cid = blockIdx.x;                 // 64 = 32b * 2dir
    int b = cid >> 1, dir = cid & 1;
    int len = new_len[b];
    const float* Whh = dir ? Whh_b : Whh_f;
    lstm_chain(Whh, xproj + ((size_t)b << 20), lstm_packed + (size_t)b*T_*256,
               0, len, dir, dir,
               hinit + (dir*B_ + b)*HD_, cinit + (dir*B_ + b)*HD_,
               nullptr, nullptr);
}

// ---------------- emission: em[b][p][s] = lstm2[b][p][:] . Wlin[s][:] + blin[s] ----------------
__global__ void __launch_bounds__(256)
emission_kernel(const float* __restrict__ lstm_packed, const float* __restrict__ Wlin,
                const float* __restrict__ blin, float* __restrict__ emis,
                const int* __restrict__ new_len)
{
    int b  = blockIdx.y;
    int nl = new_len[b];
    int p0 = blockIdx.x * 16;
    if (p0 >= nl) return;
    int pl = threadIdx.x >> 4, s = threadIdx.x & 15;
    int p  = p0 + pl;
    const float4* xr = (const float4*)(lstm_packed + ((size_t)b*T_ + p) * 256);
    const float4* wr = (const float4*)(Wlin + (size_t)s * 256);
    float ax = 0.f, ay = 0.f, az = 0.f, aw = 0.f;
    #pragma unroll
    for (int i = 0; i < 64; i++) {
        float4 a = xr[i]; float4 ww = wr[i];
        ax = fmaf(a.x, ww.x, ax); ay = fmaf(a.y, ww.y, ay);
        az = fmaf(a.z, ww.z, az); aw = fmaf(a.w, ww.w, aw);
    }
    if (p < nl) emis[((size_t)b*T_ + p)*K_ + s] = (ax + ay) + (az + aw) + blin[s];
}

// ---------------- Viterbi: one block (1 wave) per batch element ----------------
__global__ void __launch_bounds__(64)
viterbi_kernel(const float* __restrict__ emis, const float* __restrict__ start,
               const float* __restrict__ trans, const float* __restrict__ endv,
               const int* __restrict__ new_len, float* __restrict__ out)
{
    int b    = blockIdx.x;
    int nl   = new_len[b];
    int lane = threadIdx.x;          // 64 lanes: 4 q-groups x 16 states
    int s    = lane & 15, q4 = lane >> 4;

    __shared__ unsigned char hist[T_ * K_];   // 16 KB
    __shared__ unsigned char tagb[T_];

    float tr[4];
    #pragma unroll
    for (int jj = 0; jj < 4; jj++) tr[jj] = trans[(q4*4 + jj)*K_ + s];

    const float* em = emis + (size_t)b * T_ * K_;
    float sc = start[s] + em[s];     // p = 0 (always valid)

    for (int p = 1; p < nl; p++) {
        float e = em[p*K_ + s];
        float m = -3.4e38f; int a = 0;
        #pragma unroll
        for (int jj = 0; jj < 4; jj++) {
            int q   = q4*4 + jj;
            float sq = __shfl(sc, q, 16);
            float v  = sq + tr[jj];
            if (v > m) { m = v; a = q; }
        }
        #pragma unroll
        for (int d = 16; d < 64; d <<= 1) {
            float mo = __shfl_xor(m, d);
            int   ao = __shfl_xor(a, d);
            if (mo > m || (mo == m && ao < a)) { m = mo; a = ao; }
        }
        sc = m + e;
        if (lane < K_) hist[p*K_ + s] = (unsigned char)a;
    }

    // final = sc + end; best/argmax (first index on ties)
    float m = sc + endv[s]; int a = s;
    #pragma unroll
    for (int d = 1; d < 16; d <<= 1) {
        float mo = __shfl_xor(m, d);
        int   ao = __shfl_xor(a, d);
        if (mo > m || (mo == m && ao < a)) { m = mo; a = ao; }
    }
    int last = a;
    if (lane == 0) out[T_*B_ + b] = m;
    __syncthreads();

    for (int i = lane; i < T_; i += 64) tagb[i] = (unsigned char)last;
    __syncthreads();
    if (lane == 0) {
        int cur = last;
        for (int j = nl - 2; j >= 0; j--) {
            cur = hist[(j+1)*K_ + cur];
            tagb[j] = (unsigned char)cur;
        }
    }
    __syncthreads();
    for (int i = lane; i < T_; i += 64) out[(size_t)i*B_ + b] = (float)tagb[i];
}

// ---------------- host ----------------
extern "C" void kernel_launch(void* const* d_in, const int* in_sizes, int n_in,
                              void* d_out, int out_size, void* d_ws, size_t ws_size,
                              hipStream_t stream)
{
    (void)in_sizes; (void)n_in; (void)out_size; (void)ws_size;
    const int*   texts   = (const int*)  d_in[0];
    const int*   lengths = (const int*)  d_in[1];
    const float* emb     = (const float*)d_in[2];
    const float* Wih_f   = (const float*)d_in[3];
    const float* Whh_f   = (const float*)d_in[4];
    const float* bih_f   = (const float*)d_in[5];
    const float* bhh_f   = (const float*)d_in[6];
    const float* Wih_b   = (const float*)d_in[7];
    const float* Whh_b   = (const float*)d_in[8];
    const float* bih_b   = (const float*)d_in[9];
    const float* bhh_b   = (const float*)d_in[10];
    const float* Wlin    = (const float*)d_in[11];
    const float* blin    = (const float*)d_in[12];
    const float* c_start = (const float*)d_in[13];
    const float* c_trans = (const float*)d_in[14];
    const float* c_end   = (const float*)d_in[15];
    float* out = (float*)d_out;

    // workspace carve (~163 MB total, all 16B-aligned)
    char* w = (char*)d_ws;
    int*   seg_off     = (int*)(w);                      // 256 ints
    int*   new_len     = (int*)(w + 1024);               // 32 ints
    float* bias1       = (float*)(w + 4096);             // 1024 f
    float* WT1         = (float*)(w + 8192);             // 262144 f (1 MB)
    float* hinit       = (float*)(w + 8192 + 1048576);   // 8192 f
    float* cinit       = hinit + 8192;                   // 8192 f
    float* lstm_packed = cinit + 8192;                   // 32*1024*256 f (32 MB)
    float* xproj       = lstm_packed + (size_t)B_*T_*256;    // 32*1024*1024 f (128 MB)
    float* emis        = xproj + ((size_t)B_ << 20);         // 32*1024*16 f (2 MB)

    prep_kernel<<<128, 256, 0, stream>>>(lengths, seg_off, new_len,
                                         bih_f, bhh_f, bih_b, bhh_b, bias1,
                                         Wih_f, Wih_b, WT1);
    proj_kernel<0><<<dim3(32, 4, B_), 256, 0, stream>>>(texts, emb, WT1, bias1,
                                                        lstm_packed, xproj, seg_off, new_len);
    lstm1_kernel<<<512, 512, 0, stream>>>(lengths, seg_off, Whh_f, Whh_b,
                                          xproj, lstm_packed, hinit, cinit);
    proj_kernel<1><<<dim3(32, 4, B_), 256, 0, stream>>>(texts, emb, WT1, bias1,
                                                        lstm_packed, xproj, seg_off, new_len);
    lstm2_kernel<<<64, 512, 0, stream>>>(new_len, Whh_f, Whh_b,
                                         xproj, lstm_packed, hinit, cinit);
    emission_kernel<<<dim3(64, B_), 256, 0, stream>>>(lstm_packed, Wlin, blin, emis, new_len);
    viterbi_kernel<<<B_, 64, 0, stream>>>(emis, c_start, c_trans, c_end, new_len, out);
}

// Round 4
// 1581.679 us; speedup vs baseline: 1.6546x; 1.1739x over previous
//
#include <hip/hip_runtime.h>
#include <cstdint>
#include <cstddef>

// BiLSTM-CRF forward, MI355X fp32 implementation.
// Pipeline: prep -> proj1(emb gather GEMM) -> lstm1(512 chains) -> proj2(GEMM)
//           -> lstm2(64 chains) -> emission -> viterbi(+backtrace).
// Only valid (packed) tokens are computed; tail positions provably don't
// affect outputs (mask freezes LSTM2 state and Viterbi score/backtrace).
//
// R3: kill the per-step vmcnt(0) barrier drain. hipcc emits
// "s_waitcnt vmcnt(0)" before every s_barrier; R0-R2 issued global loads
// (next xv) + a global store (hn) inside each step, so every step paid a
// ~900-cyc HBM round trip at the barrier. Now steps are grouped by K=8:
// per group, reducer threads flush 8 buffered hn stores and burst-load
// 8 steps x 4 gates of xv into registers; the 8 inner steps touch global
// memory not at all -> barrier waits are lgkm-only, drain amortized 8x.

#define B_    32
#define NSEG_ 8
#define S_    128
#define T_    1024
#define E_    256
#define HD_   128
#define G_    512   // 4*HD
#define K_    16
#define KS_   8     // steps per group (global-drain amortization)

#define PIN4(v) asm volatile("" : "+v"((v).x), "+v"((v).y), "+v"((v).z), "+v"((v).w))

// ---------------- prep: seg offsets, fused bias, transposed Wih ----------------
__global__ void prep_kernel(const int* __restrict__ lengths,
                            int* __restrict__ seg_off, int* __restrict__ new_len,
                            const float* __restrict__ bih_f, const float* __restrict__ bhh_f,
                            const float* __restrict__ bih_b, const float* __restrict__ bhh_b,
                            float* __restrict__ bias1,
                            const float* __restrict__ Wih_f, const float* __restrict__ Wih_b,
                            float* __restrict__ WT1)
{
    int gtid = blockIdx.x * blockDim.x + threadIdx.x;
    if (gtid < B_) {
        int acc = 0;
        for (int s = 0; s < NSEG_; s++) { seg_off[gtid*NSEG_ + s] = acc; acc += lengths[gtid*NSEG_ + s]; }
        new_len[gtid] = acc;
    }
    if (gtid < 512)       bias1[gtid] = bih_f[gtid] + bhh_f[gtid];
    else if (gtid < 1024) bias1[gtid] = bih_b[gtid-512] + bhh_b[gtid-512];
    // WT1[k][j] (256 x 1024): j<512 -> Wih_f[j][k], else Wih_b[j-512][k]
    for (int e = gtid; e < 256*1024; e += gridDim.x * blockDim.x) {
        int k = e >> 10, j = e & 1023;
        WT1[e] = (j < 512) ? Wih_f[j*E_ + k] : Wih_b[(j-512)*E_ + k];
    }
}

// ---------------- projection GEMM: xproj[b][p][j] = A[p][:] . WT1[:][j] + bias1[j] ----------------
// MODE 0: A row = emb_table[texts[...]] (gather); MODE 1: A row = lstm_packed[b][p][:]
template <int MODE>
__global__ void __launch_bounds__(256, 4)
proj_kernel(const int* __restrict__ texts, const float* __restrict__ emb,
            const float* __restrict__ WT1, const float* __restrict__ bias1,
            const float* __restrict__ lstm_packed, float* __restrict__ xproj,
            const int* __restrict__ seg_off, const int* __restrict__ new_len)
{
    int b  = blockIdx.z;
    int nl = new_len[b];
    int p0 = blockIdx.x * 32;
    if (p0 >= nl) return;
    int j0 = blockIdx.y * 256;

    __shared__ __align__(16) float As[32][256];
    __shared__ const float* rowp[32];
    int tid = threadIdx.x;
    if (tid < 32) {
        int p = p0 + tid;
        const float* r = emb;  // dummy row for invalid p
        if (p < nl) {
            if (MODE == 0) {
                int sg = 0;
                #pragma unroll
                for (int q = 1; q < NSEG_; q++) if (seg_off[b*NSEG_ + q] <= p) sg = q;
                int t   = p - seg_off[b*NSEG_ + sg];
                int tok = texts[(b*NSEG_ + sg)*S_ + t];
                r = emb + (size_t)tok * E_;
            } else {
                r = lstm_packed + ((size_t)b*T_ + p) * 256;
            }
        }
        rowp[tid] = r;
    }
    __syncthreads();
    #pragma unroll 4
    for (int i = 0; i < 32; i++) As[i][tid] = rowp[i][tid];
    __syncthreads();

    int pg = tid >> 6;        // 0..3 -> rows pg*8 .. pg*8+7
    int jg = tid & 63;        // cols j0 + jg*4 .. +3
    int j  = j0 + jg*4;
    float acc[8][4];
    #pragma unroll
    for (int i = 0; i < 8; i++) { acc[i][0]=0.f; acc[i][1]=0.f; acc[i][2]=0.f; acc[i][3]=0.f; }

    const float* wbase = WT1 + j;
    for (int k = 0; k < 256; k += 4) {
        float4 w0 = *(const float4*)(wbase + (size_t)(k+0)*1024);
        float4 w1 = *(const float4*)(wbase + (size_t)(k+1)*1024);
        float4 w2 = *(const float4*)(wbase + (size_t)(k+2)*1024);
        float4 w3 = *(const float4*)(wbase + (size_t)(k+3)*1024);
        #pragma unroll
        for (int i = 0; i < 8; i++) {
            float4 a = *(const float4*)&As[pg*8 + i][k];
            acc[i][0] = fmaf(a.w, w3.x, fmaf(a.z, w2.x, fmaf(a.y, w1.x, fmaf(a.x, w0.x, acc[i][0]))));
            acc[i][1] = fmaf(a.w, w3.y, fmaf(a.z, w2.y, fmaf(a.y, w1.y, fmaf(a.x, w0.y, acc[i][1]))));
            acc[i][2] = fmaf(a.w, w3.z, fmaf(a.z, w2.z, fmaf(a.y, w1.z, fmaf(a.x, w0.z, acc[i][2]))));
            acc[i][3] = fmaf(a.w, w3.w, fmaf(a.z, w2.w, fmaf(a.y, w1.w, fmaf(a.x, w0.w, acc[i][3]))));
        }
    }
    float4 bs = *(const float4*)(bias1 + j);
    #pragma unroll
    for (int i = 0; i < 8; i++) {
        int p = p0 + pg*8 + i;
        if (p < nl) {
            float4 r;
            r.x = acc[i][0] + bs.x; r.y = acc[i][1] + bs.y;
            r.z = acc[i][2] + bs.z; r.w = acc[i][3] + bs.w;
            *(float4*)(xproj + (((size_t)b*T_ + p) << 10) + j) = r;
        }
    }
}

// ---------------- LSTM chain v4: K-grouped global access ----------------
__device__ __forceinline__ float sig_f(float x) { return 1.0f / (1.0f + __expf(-x)); }
__device__ __forceinline__ float tanh_f(float x) {
    float xc = fminf(fmaxf(x, -15.0f), 15.0f);
    float e  = __expf(-2.0f * xc);
    return (1.0f - e) / (1.0f + e);
}

__device__ __forceinline__ void lstm_chain(
    const float* __restrict__ Whh,     // [512][128] row-major, this dir
    const float* __restrict__ xp,      // xproj for this b: [1024][1024] (bias folded in)
    float* __restrict__ outp,          // lstm_packed for this b: [1024][256]
    int p_base, int len, int dir, int rev,
    const float* __restrict__ h0, const float* __restrict__ c0,
    float* __restrict__ hT, float* __restrict__ cT)
{
    __shared__ __align__(16) float  h_sh[HD_];
    __shared__ __align__(16) float4 psum[4*HD_];   // [q][j], conflict-free lane order
    int t = threadIdx.x;          // 0..511
    int j = t & 127, q = t >> 7;  // per-wave q is uniform -> h reads are pure broadcast

    // Weights: gate rows j+128g, k in [32q, 32q+32). Pinned into VGPRs.
    float4 w[4][8];
    #pragma unroll
    for (int g = 0; g < 4; g++) {
        const float4* wr = (const float4*)(Whh + (size_t)(j + 128*g) * HD_ + 32*q);
        #pragma unroll
        for (int i = 0; i < 8; i++) { w[g][i] = wr[i]; PIN4(w[g][i]); }
    }

    float c_reg = 0.0f;
    if (t < HD_) {
        h_sh[t] = h0 ? h0[t] : 0.0f;
        c_reg   = c0 ? c0[t] : 0.0f;
    }
    __syncthreads();

    const float* xcol = xp + dir * G_ + j;   // gate g at +128*g
    const int    oco  = dir * HD_ + j;

    float xvi[KS_], xvf[KS_], xvg[KS_], xvo[KS_], hbuf[KS_];

    for (int gs = 0; gs < len; gs += KS_) {
        // ---- group prologue: the ONLY global traffic (drained once/group) ----
        if (t < HD_) {
            if (gs > 0) {
                #pragma unroll
                for (int u = 0; u < KS_; u++) {          // prev group always full
                    int s = gs - KS_ + u;
                    int p = p_base + (rev ? (len - 1 - s) : s);
                    outp[(size_t)p * 256 + oco] = hbuf[u];
                }
            }
            #pragma unroll
            for (int u = 0; u < KS_; u++) {
                int s = gs + u;
                if (s < len) {
                    int p = p_base + (rev ? (len - 1 - s) : s);
                    const float* r = xcol + ((size_t)p << 10);
                    xvi[u] = r[0]; xvf[u] = r[128]; xvg[u] = r[256]; xvo[u] = r[384];
                }
            }
        }
        // ---- 8 steps, zero global ops, lgkm-only barriers ----
        #pragma unroll
        for (int u = 0; u < KS_; u++) {
            if (gs + u < len) {                          // block-uniform predicate
                const float4* hv = (const float4*)h_sh + q * 8;
                float4 a0 = make_float4(0.f,0.f,0.f,0.f);
                float4 a1 = a0, a2 = a0, a3 = a0;
                #pragma unroll
                for (int i = 0; i < 8; i++) {
                    float4 h4 = hv[i];
                    a0.x = fmaf(h4.x, w[0][i].x, a0.x); a0.y = fmaf(h4.y, w[0][i].y, a0.y);
                    a0.z = fmaf(h4.z, w[0][i].z, a0.z); a0.w = fmaf(h4.w, w[0][i].w, a0.w);
                    a1.x = fmaf(h4.x, w[1][i].x, a1.x); a1.y = fmaf(h4.y, w[1][i].y, a1.y);
                    a1.z = fmaf(h4.z, w[1][i].z, a1.z); a1.w = fmaf(h4.w, w[1][i].w, a1.w);
                    a2.x = fmaf(h4.x, w[2][i].x, a2.x); a2.y = fmaf(h4.y, w[2][i].y, a2.y);
                    a2.z = fmaf(h4.z, w[2][i].z, a2.z); a2.w = fmaf(h4.w, w[2][i].w, a2.w);
                    a3.x = fmaf(h4.x, w[3][i].x, a3.x); a3.y = fmaf(h4.y, w[3][i].y, a3.y);
                    a3.z = fmaf(h4.z, w[3][i].z, a3.z); a3.w = fmaf(h4.w, w[3][i].w, a3.w);
                }
                psum[q*128 + j] = make_float4((a0.x+a0.y)+(a0.z+a0.w),
                                              (a1.x+a1.y)+(a1.z+a1.w),
                                              (a2.x+a2.y)+(a2.z+a2.w),
                                              (a3.x+a3.y)+(a3.z+a3.w));
                __syncthreads();
                if (t < HD_) {
                    float4 p0 = psum[j], p1 = psum[128 + j], p2 = psum[256 + j], p3 = psum[384 + j];
                    float gi = xvi[u] + ((p0.x + p1.x) + (p2.x + p3.x));
                    float gf = xvf[u] + ((p0.y + p1.y) + (p2.y + p3.y));
                    float gg = xvg[u] + ((p0.z + p1.z) + (p2.z + p3.z));
                    float go = xvo[u] + ((p0.w + p1.w) + (p2.w + p3.w));
                    float cn = sig_f(gf) * c_reg + sig_f(gi) * tanh_f(gg);
                    c_reg = cn;
                    float hn = sig_f(go) * tanh_f(cn);
                    h_sh[j] = hn;
                    hbuf[u] = hn;
                }
                __syncthreads();
            }
        }
    }
    // final flush of the last (possibly partial) group
    if (t < HD_ && len > 0) {
        int gs = ((len - 1) / KS_) * KS_;
        #pragma unroll
        for (int u = 0; u < KS_; u++) {
            int s = gs + u;
            if (s < len) {
                int p = p_base + (rev ? (len - 1 - s) : s);
                outp[(size_t)p * 256 + oco] = hbuf[u];
            }
        }
    }
    if (hT != nullptr && t < HD_) { hT[t] = h_sh[t]; cT[t] = c_reg; }
}

__global__ void __launch_bounds__(512, 2)
lstm1_kernel(const int* __restrict__ lengths, const int* __restrict__ seg_off,
             const float* __restrict__ Whh_f, const float* __restrict__ Whh_b,
             const float* __restrict__ xproj, float* __restrict__ lstm_packed,
             float* __restrict__ hinit, float* __restrict__ cinit)
{
    int cid = blockIdx.x;                 // 512 = 32b * 8seg * 2dir
    int b = cid >> 4, seg = (cid >> 1) & 7, dir = cid & 1;
    int len = lengths[b*NSEG_ + seg];
    int pb  = seg_off[b*NSEG_ + seg];
    const float* Whh = dir ? Whh_b : Whh_f;
    float* hT = nullptr; float* cT = nullptr;
    if (seg == NSEG_ - 1) {               // final states feed LSTM2 init
        hT = hinit + (dir*B_ + b)*HD_;
        cT = cinit + (dir*B_ + b)*HD_;
    }
    lstm_chain(Whh, xproj + ((size_t)b << 20), lstm_packed + (size_t)b*T_*256,
               pb, len, dir, dir, nullptr, nullptr, hT, cT);
}

__global__ void __launch_bounds__(512, 2)
lstm2_kernel(const int* __restrict__ new_len,
             const float* __restrict__ Whh_f, const float* __restrict__ Whh_b,
             const float* __restrict__ xproj, float* __restrict__ lstm_packed,
             const float* __restrict__ hinit, const float* __restrict__ cinit)
{
    int cid = blockIdx.x;                 // 64 = 32b * 2dir
    int b = cid >> 1, dir = cid & 1;
    int len = new_len[b];
    const float* Whh = dir ? Whh_b : Whh_f;
    lstm_chain(Whh, xproj + ((size_t)b << 20), lstm_packed + (size_t)b*T_*256,
               0, len, dir, dir,
               hinit + (dir*B_ + b)*HD_, cinit + (dir*B_ + b)*HD_,
               nullptr, nullptr);
}

// ---------------- emission: em[b][p][s] = lstm2[b][p][:] . Wlin[s][:] + blin[s] ----------------
__global__ void __launch_bounds__(256)
emission_kernel(const float* __restrict__ lstm_packed, const float* __restrict__ Wlin,
                const float* __restrict__ blin, float* __restrict__ emis,
                const int* __restrict__ new_len)
{
    int b  = blockIdx.y;
    int nl = new_len[b];
    int p0 = blockIdx.x * 16;
    if (p0 >= nl) return;
    int pl = threadIdx.x >> 4, s = threadIdx.x & 15;
    int p  = p0 + pl;
    const float4* xr = (const float4*)(lstm_packed + ((size_t)b*T_ + p) * 256);
    const float4* wr = (const float4*)(Wlin + (size_t)s * 256);
    float ax = 0.f, ay = 0.f, az = 0.f, aw = 0.f;
    #pragma unroll
    for (int i = 0; i < 64; i++) {
        float4 a = xr[i]; float4 ww = wr[i];
        ax = fmaf(a.x, ww.x, ax); ay = fmaf(a.y, ww.y, ay);
        az = fmaf(a.z, ww.z, az); aw = fmaf(a.w, ww.w, aw);
    }
    if (p < nl) emis[((size_t)b*T_ + p)*K_ + s] = (ax + ay) + (az + aw) + blin[s];
}

// ---------------- Viterbi: one block (1 wave) per batch element ----------------
__global__ void __launch_bounds__(64)
viterbi_kernel(const float* __restrict__ emis, const float* __restrict__ start,
               const float* __restrict__ trans, const float* __restrict__ endv,
               const int* __restrict__ new_len, float* __restrict__ out)
{
    int b    = blockIdx.x;
    int nl   = new_len[b];
    int lane = threadIdx.x;          // 64 lanes: 4 q-groups x 16 states
    int s    = lane & 15, q4 = lane >> 4;

    __shared__ unsigned char hist[T_ * K_];   // 16 KB
    __shared__ unsigned char tagb[T_];

    float tr[4];
    #pragma unroll
    for (int jj = 0; jj < 4; jj++) tr[jj] = trans[(q4*4 + jj)*K_ + s];

    const float* em = emis + (size_t)b * T_ * K_;
    float sc = start[s] + em[s];     // p = 0 (always valid)

    for (int p = 1; p < nl; p++) {
        float e = em[p*K_ + s];
        float m = -3.4e38f; int a = 0;
        #pragma unroll
        for (int jj = 0; jj < 4; jj++) {
            int q   = q4*4 + jj;
            float sq = __shfl(sc, q, 16);
            float v  = sq + tr[jj];
            if (v > m) { m = v; a = q; }
        }
        #pragma unroll
        for (int d = 16; d < 64; d <<= 1) {
            float mo = __shfl_xor(m, d);
            int   ao = __shfl_xor(a, d);
            if (mo > m || (mo == m && ao < a)) { m = mo; a = ao; }
        }
        sc = m + e;
        if (lane < K_) hist[p*K_ + s] = (unsigned char)a;
    }

    // final = sc + end; best/argmax (first index on ties)
    float m = sc + endv[s]; int a = s;
    #pragma unroll
    for (int d = 1; d < 16; d <<= 1) {
        float mo = __shfl_xor(m, d);
        int   ao = __shfl_xor(a, d);
        if (mo > m || (mo == m && ao < a)) { m = mo; a = ao; }
    }
    int last = a;
    if (lane == 0) out[T_*B_ + b] = m;
    __syncthreads();

    for (int i = lane; i < T_; i += 64) tagb[i] = (unsigned char)last;
    __syncthreads();
    if (lane == 0) {
        int cur = last;
        for (int j = nl - 2; j >= 0; j--) {
            cur = hist[(j+1)*K_ + cur];
            tagb[j] = (unsigned char)cur;
        }
    }
    __syncthreads();
    for (int i = lane; i < T_; i += 64) out[(size_t)i*B_ + b] = (float)tagb[i];
}

// ---------------- host ----------------
extern "C" void kernel_launch(void* const* d_in, const int* in_sizes, int n_in,
                              void* d_out, int out_size, void* d_ws, size_t ws_size,
                              hipStream_t stream)
{
    (void)in_sizes; (void)n_in; (void)out_size; (void)ws_size;
    const int*   texts   = (const int*)  d_in[0];
    const int*   lengths = (const int*)  d_in[1];
    const float* emb     = (const float*)d_in[2];
    const float* Wih_f   = (const float*)d_in[3];
    const float* Whh_f   = (const float*)d_in[4];
    const float* bih_f   = (const float*)d_in[5];
    const float* bhh_f   = (const float*)d_in[6];
    const float* Wih_b   = (const float*)d_in[7];
    const float* Whh_b   = (const float*)d_in[8];
    const float* bih_b   = (const float*)d_in[9];
    const float* bhh_b   = (const float*)d_in[10];
    const float* Wlin    = (const float*)d_in[11];
    const float* blin    = (const float*)d_in[12];
    const float* c_start = (const float*)d_in[13];
    const float* c_trans = (const float*)d_in[14];
    const float* c_end   = (const float*)d_in[15];
    float* out = (float*)d_out;

    // workspace carve (~163 MB total, all 16B-aligned)
    char* w = (char*)d_ws;
    int*   seg_off     = (int*)(w);                      // 256 ints
    int*   new_len     = (int*)(w + 1024);               // 32 ints
    float* bias1       = (float*)(w + 4096);             // 1024 f
    float* WT1         = (float*)(w + 8192);             // 262144 f (1 MB)
    float* hinit       = (float*)(w + 8192 + 1048576);   // 8192 f
    float* cinit       = hinit + 8192;                   // 8192 f
    float* lstm_packed = cinit + 8192;                   // 32*1024*256 f (32 MB)
    float* xproj       = lstm_packed + (size_t)B_*T_*256;    // 32*1024*1024 f (128 MB)
    float* emis        = xproj + ((size_t)B_ << 20);         // 32*1024*16 f (2 MB)

    prep_kernel<<<128, 256, 0, stream>>>(lengths, seg_off, new_len,
                                         bih_f, bhh_f, bih_b, bhh_b, bias1,
                                         Wih_f, Wih_b, WT1);
    proj_kernel<0><<<dim3(32, 4, B_), 256, 0, stream>>>(texts, emb, WT1, bias1,
                                                        lstm_packed, xproj, seg_off, new_len);
    lstm1_kernel<<<512, 512, 0, stream>>>(lengths, seg_off, Whh_f, Whh_b,
                                          xproj, lstm_packed, hinit, cinit);
    proj_kernel<1><<<dim3(32, 4, B_), 256, 0, stream>>>(texts, emb, WT1, bias1,
                                                        lstm_packed, xproj, seg_off, new_len);
    lstm2_kernel<<<64, 512, 0, stream>>>(new_len, Whh_f, Whh_b,
                                         xproj, lstm_packed, hinit, cinit);
    emission_kernel<<<dim3(64, B_), 256, 0, stream>>>(lstm_packed, Wlin, blin, emis, new_len);
    viterbi_kernel<<<B_, 64, 0, stream>>>(emis, c_start, c_trans, c_end, new_len, out);
}